// Round 6
// baseline (1471.083 us; speedup 1.0000x reference)
//
#include <hip/hip_runtime.h>
#include <hip/hip_bf16.h>

// Problem constants (from reference config)
#define CIN 256
#define COUT 256
#define HW 56
#define BATCH 8
#define L_SPATIAL 3136            // 56*56
#define K_TOTAL 2304              // CIN*3*3
#define NT 36                     // K chunks of 64
#define NH 18                     // n-chunks retained per wave (half)
#define ROWF (COUT * NT)          // 9216 floats per (b,l) row of psum
#define KSTRIDE 2312              // bf16 elems per m-row in LDS (+8 pad)
#define ATILE_BYTES (16 * KSTRIDE * 2)       // 73,984 B
#define CARRY_OFF ATILE_BYTES                // carry: 2048 f32 = 8,192 B
#define LDS_BYTES (CARRY_OFF + 8192)         // 82,176 B -> 1 WG/CU, 16 waves
#define MT_TOTAL 1568             // m-tiles (8*3136/16)
#define TILES_PER_IMG 196
#define QMAXF 127.0f
#define QMINF -128.0f

typedef short bf16x8 __attribute__((ext_vector_type(8)));
typedef float f32x4 __attribute__((ext_vector_type(4)));
typedef float f32x2 __attribute__((ext_vector_type(2)));

__device__ __forceinline__ void nt_store4(float* p, f32x4 v) {
  __builtin_nontemporal_store(v, reinterpret_cast<f32x4*>(p));
}

// ---- prep: Bsign[c][k] = sign(w) as bf16 (B^T layout = MFMA B-frag order), scale[c] = mean|w| ----
__global__ __launch_bounds__(256) void prep_kernel(
    const float* __restrict__ w, unsigned short* __restrict__ bsign,
    float* __restrict__ scale) {
  const int c = blockIdx.x;
  const int t = threadIdx.x;
  const float* row = w + (size_t)c * K_TOTAL;
  unsigned short* out = bsign + (size_t)c * K_TOTAL;
  float acc = 0.0f;
#pragma unroll
  for (int j = 0; j < 9; ++j) {
    const int k = t + 256 * j;
    const float v = row[k];
    acc += __builtin_fabsf(v);
    out[k] = (v > 0.0f) ? (unsigned short)0x3F80
           : ((v < 0.0f) ? (unsigned short)0xBF80 : (unsigned short)0);
  }
#pragma unroll
  for (int o = 32; o > 0; o >>= 1) acc += __shfl_down(acc, o, 64);
  __shared__ float red[4];
  if ((t & 63) == 0) red[t >> 6] = acc;
  __syncthreads();
  if (t == 0) scale[c] = (red[0] + red[1] + red[2] + red[3]) * (1.0f / 2304.0f);
}

// Compute 18 chunks [H*18, H*18+18), retain all in ps[]; H==0 also runs the
// saturating scan prefix (carry starts UNCLIPPED at chunk 0, matching ref).
template <int H>
__device__ __forceinline__ void compute18(
    const unsigned short* __restrict__ aptr,
    const unsigned short* __restrict__ bptr,
    f32x4* __restrict__ ps, f32x4& sacc) {
  const f32x4 zero = {0.0f, 0.0f, 0.0f, 0.0f};
  const unsigned short* ap = aptr + H * NH * 64;
  const unsigned short* bp = bptr + H * NH * 64;
  bf16x8 b0 = *reinterpret_cast<const bf16x8*>(bp);
  bf16x8 b1 = *reinterpret_cast<const bf16x8*>(bp + 32);
#pragma unroll
  for (int j = 0; j < NH; ++j) {
    bf16x8 nb0, nb1;
    if (j + 1 < NH) {                     // prefetch next B-frag
      nb0 = *reinterpret_cast<const bf16x8*>(bp + (j + 1) * 64);
      nb1 = *reinterpret_cast<const bf16x8*>(bp + (j + 1) * 64 + 32);
    }
    bf16x8 a0 = *reinterpret_cast<const bf16x8*>(ap + j * 64);
    bf16x8 a1 = *reinterpret_cast<const bf16x8*>(ap + j * 64 + 32);
    f32x4 acc = __builtin_amdgcn_mfma_f32_16x16x32_bf16(a0, b0, zero, 0, 0, 0);
    acc = __builtin_amdgcn_mfma_f32_16x16x32_bf16(a1, b1, acc, 0, 0, 0);
    ps[j] = acc;
    if (H == 0) {
      if (j == 0) {
        sacc = acc;
      } else {
#pragma unroll
        for (int e = 0; e < 4; ++e)
          sacc[e] = __builtin_amdgcn_fmed3f(sacc[e] + acc[e], QMINF, QMAXF);
      }
    }
    b0 = nb0;
    b1 = nb1;
  }
}

// ---- main: 1024 threads = 16 waves = 8 c-subtile pairs x 2 n-halves; 2 s-passes.
// psum drain is PURE-REGISTER scatter: lane (cl,q), component e already holds an
// n-contiguous 72B run psum[m0+4q+e][c][h*18..+18) -- no LDS transpose, no drain
// barriers. Each 144B (m,c) run is completed within ~20 instrs by one lane plus
// its partner-h wave (~1us apart): plain stores let L2 write-merge full 64B lines
// before eviction (R1's RMW failure was ms-scale gaps; this is us-scale).
// Store drain overlaps next-pass compute (no vmcnt(0) barriers in the way).
__global__ __launch_bounds__(1024, 4) void satconv_kernel(
    const float* __restrict__ x, const unsigned short* __restrict__ bsign,
    const float* __restrict__ scale, float* __restrict__ y_out,
    float* __restrict__ psum_out) {
  extern __shared__ char smem[];
  unsigned short* Atile = (unsigned short*)smem;        // [16][KSTRIDE] bf16
  float* carryb = (float*)(smem + CARRY_OFF);           // [8][256] f32

  const int tid = threadIdx.x;
  const int bid = blockIdx.x;
  // XCD swizzle: 8 XCDs x 196 tiles; each XCD owns one batch image.
  const int m_tile = (bid & 7) * TILES_PER_IMG + (bid >> 3);
  const int m0 = m_tile << 4;

  // ---------- build A tile: lanes 0-15 = consecutive m (= consecutive ow) ----------
  {
    const int ml = tid & 15;
    const int grp = tid >> 4;                 // 0..63
    const int m = m0 + ml;
    const int b = m / L_SPATIAL;
    const int l = m - b * L_SPATIAL;
    const int oh = l / HW;
    const int ow = l - oh * HW;
    const float* xb = x + (size_t)b * (CIN * L_SPATIAL);
    unsigned short* arow = Atile + ml * KSTRIDE;
    for (int r = grp; r < 768; r += 64) {     // r = ci*3 + kh; 12 iters
      const int ci = r / 3;
      const int kh = r - ci * 3;
      const int hh = oh + kh - 1;
      const bool hv = ((unsigned)hh < (unsigned)HW);
      const float* xr = xb + (ci * HW + hh) * HW;
      const int kb = ci * 9 + kh * 3;
#pragma unroll
      for (int kw = 0; kw < 3; ++kw) {
        const int wv = ow + kw - 1;
        float v = 0.0f;
        if (hv && ((unsigned)wv < (unsigned)HW)) v = xr[wv];
        __hip_bfloat16 bv = __float2bfloat16(v);
        arow[kb + kw] = *reinterpret_cast<unsigned short*>(&bv);
      }
    }
  }

  const int lane = tid & 63;
  const int wave = tid >> 6;                  // 0..15
  const int cl = lane & 15;
  const int q = lane >> 4;
  const int cs = wave >> 1;                   // 0..7: c-subtile pair id
  const int h = wave & 1;                     // n-half

  // hoist scalar loads before the store streams
  const float sc_s0 = scale[cs * 16 + cl];
  const float sc_s1 = scale[128 + cs * 16 + cl];

  __syncthreads();

  const unsigned short* aptr = Atile + cl * KSTRIDE + q * 8;
  const int b_img = m0 / L_SPATIAL;           // WG never crosses batch boundary
  const int l0 = m0 - b_img * L_SPATIAL;

  for (int s = 0; s < 2; ++s) {
    const int csub0 = (s << 7) + (cs << 4);   // c-subtile base (0..240)
    const int c = csub0 + cl;
    const unsigned short* bptr = bsign + (size_t)c * K_TOTAL + q * 8;

    f32x4 ps[NH];
    f32x4 sacc = {0.0f, 0.0f, 0.0f, 0.0f};
    if (h == 0) compute18<0>(aptr, bptr, ps, sacc);
    else        compute18<1>(aptr, bptr, ps, sacc);

    // ---- carry hand-off: h0 -> h1 (per (cs, cl, q), f32x4 over the 4 m's) ----
    // At this point outstanding vmem is ~nil (B loads consumed; s0 drain had the
    // whole s1 compute to complete), so __syncthreads' vmcnt(0) is cheap here.
    if (h == 0)
      *reinterpret_cast<f32x4*>(carryb + cs * 256 + lane * 4) = sacc;
    __syncthreads();
    if (h == 1) {
      f32x4 cin = *reinterpret_cast<const f32x4*>(carryb + cs * 256 + lane * 4);
#pragma unroll
      for (int j = 0; j < NH; ++j) {
#pragma unroll
        for (int e = 0; e < 4; ++e)
          cin[e] = __builtin_amdgcn_fmed3f(cin[e] + ps[j][e], QMINF, QMAXF);
      }
      const float sc = (s == 0) ? sc_s0 : sc_s1;
      f32x4 yv;
#pragma unroll
      for (int e = 0; e < 4; ++e) yv[e] = cin[e] * sc;
      nt_store4(y_out + ((size_t)b_img * COUT + c) * L_SPATIAL + l0 + (q << 2), yv);
    }

    // ---- psum drain: register scatter, no barriers. Lane (cl,q) component e owns
    // the 72B run psum[m0+4q+e][c][h*18 .. h*18+18). h=0 runs are 16B-aligned
    // (c*144B); h=1 runs start at +72B (8B-aligned) -> f32x2 first.
    {
      float* prow = psum_out + (size_t)(m0 + (q << 2)) * ROWF + (size_t)c * NT + h * NH;
#pragma unroll
      for (int e = 0; e < 4; ++e) {
        float* pr = prow + (size_t)e * ROWF;
        if (h == 0) {
#pragma unroll
          for (int g = 0; g < 4; ++g) {
            f32x4 v = {ps[4 * g + 0][e], ps[4 * g + 1][e],
                       ps[4 * g + 2][e], ps[4 * g + 3][e]};
            *reinterpret_cast<f32x4*>(pr + 4 * g) = v;
          }
          f32x2 t = {ps[16][e], ps[17][e]};
          *reinterpret_cast<f32x2*>(pr + 16) = t;
        } else {
          f32x2 t = {ps[0][e], ps[1][e]};
          *reinterpret_cast<f32x2*>(pr) = t;
#pragma unroll
          for (int g = 0; g < 4; ++g) {
            f32x4 v = {ps[4 * g + 2][e], ps[4 * g + 3][e],
                       ps[4 * g + 4][e], ps[4 * g + 5][e]};
            *reinterpret_cast<f32x4*>(pr + 2 + 4 * g) = v;
          }
        }
      }
    }
    // No pass-end barrier needed: h1's carry read completed (data-dependence via y)
    // long before h0's next carry write (which follows s1's ~10us compute).
  }
}

extern "C" void kernel_launch(void* const* d_in, const int* in_sizes, int n_in,
                              void* d_out, int out_size, void* d_ws, size_t ws_size,
                              hipStream_t stream) {
  const float* x = (const float*)d_in[0];
  const float* w = (const float*)d_in[1];
  float* y = (float*)d_out;
  float* psum = y + (size_t)BATCH * COUT * L_SPATIAL;            // y is 6,422,528 floats
  unsigned short* bsign = (unsigned short*)d_ws;                 // 256*2304*2 = 1,179,648 B
  float* scale = (float*)((char*)d_ws + (size_t)COUT * K_TOTAL * 2);

  prep_kernel<<<COUT, 256, 0, stream>>>(w, bsign, scale);

  hipFuncSetAttribute(reinterpret_cast<const void*>(satconv_kernel),
                      hipFuncAttributeMaxDynamicSharedMemorySize, LDS_BYTES);
  satconv_kernel<<<MT_TOTAL, 1024, LDS_BYTES, stream>>>(
      x, bsign, scale, y, psum);
}

// Round 9
// 1193.877 us; speedup vs baseline: 1.2322x; 1.2322x over previous
//
#include <hip/hip_runtime.h>
#include <hip/hip_bf16.h>

// Problem constants (from reference config)
#define CIN 256
#define COUT 256
#define HW 56
#define BATCH 8
#define L_SPATIAL 3136            // 56*56
#define K_TOTAL 2304              // CIN*3*3
#define NT 36                     // K chunks of 64
#define NH 18                     // n-chunks retained per wave (half)
#define ROWF (COUT * NT)          // 9216 floats per (b,l) row of psum
#define KSTRIDE 2312              // bf16 elems per m-row in LDS (+8 pad)
#define ATILE_BYTES (16 * KSTRIDE * 2)       // 73,984 B
#define STAGE_OFF ATILE_BYTES                // stage: 8 pairs x 2304 f32 = 73,728 B
#define CARRY_OFF (ATILE_BYTES + 73728)      // carry: 2048 f32 = 8,192 B
#define LDS_BYTES (CARRY_OFF + 8192)         // 155,904 B <= 160 KiB -> 1 WG/CU, 16 waves
#define MT_TOTAL 1568             // m-tiles (8*3136/16)
#define TILES_PER_IMG 196
#define QMAXF 127.0f
#define QMINF -128.0f

typedef short bf16x8 __attribute__((ext_vector_type(8)));
typedef float f32x4 __attribute__((ext_vector_type(4)));
typedef float f32x2 __attribute__((ext_vector_type(2)));

__device__ __forceinline__ void nt_store4(float* p, f32x4 v) {
  __builtin_nontemporal_store(v, reinterpret_cast<f32x4*>(p));
}

// LGKM-only barrier: orders LDS (ds) ops across the workgroup WITHOUT draining
// outstanding global stores (vmcnt). __syncthreads() would emit
// s_waitcnt vmcnt(0) before s_barrier -- a synchronous ~73.7KB NT-store drain at
// per-CU-share write BW (~3us) every rg-round (R6 post-mortem arithmetic).
// Memory-clobber asm on both sides fences compiler reordering of ds ops.
__device__ __forceinline__ void lgkm_barrier() {
  __builtin_amdgcn_sched_barrier(0);
  asm volatile("s_waitcnt lgkmcnt(0)" ::: "memory");
  __builtin_amdgcn_s_barrier();
  asm volatile("" ::: "memory");
  __builtin_amdgcn_sched_barrier(0);
}

// ---- prep: Bsign[c][k] = sign(w) as bf16 (B^T layout = MFMA B-frag order), scale[c] = mean|w| ----
__global__ __launch_bounds__(256) void prep_kernel(
    const float* __restrict__ w, unsigned short* __restrict__ bsign,
    float* __restrict__ scale) {
  const int c = blockIdx.x;
  const int t = threadIdx.x;
  const float* row = w + (size_t)c * K_TOTAL;
  unsigned short* out = bsign + (size_t)c * K_TOTAL;
  float acc = 0.0f;
#pragma unroll
  for (int j = 0; j < 9; ++j) {
    const int k = t + 256 * j;
    const float v = row[k];
    acc += __builtin_fabsf(v);
    out[k] = (v > 0.0f) ? (unsigned short)0x3F80
           : ((v < 0.0f) ? (unsigned short)0xBF80 : (unsigned short)0);
  }
#pragma unroll
  for (int o = 32; o > 0; o >>= 1) acc += __shfl_down(acc, o, 64);
  __shared__ float red[4];
  if ((t & 63) == 0) red[t >> 6] = acc;
  __syncthreads();
  if (t == 0) scale[c] = (red[0] + red[1] + red[2] + red[3]) * (1.0f / 2304.0f);
}

// Compute 18 chunks [H*18, H*18+18), retain all in ps[]; H==0 also runs the
// saturating scan prefix (carry starts UNCLIPPED at chunk 0, matching ref).
template <int H>
__device__ __forceinline__ void compute18(
    const unsigned short* __restrict__ aptr,
    const unsigned short* __restrict__ bptr,
    f32x4* __restrict__ ps, f32x4& sacc) {
  const f32x4 zero = {0.0f, 0.0f, 0.0f, 0.0f};
  const unsigned short* ap = aptr + H * NH * 64;
  const unsigned short* bp = bptr + H * NH * 64;
  bf16x8 b0 = *reinterpret_cast<const bf16x8*>(bp);
  bf16x8 b1 = *reinterpret_cast<const bf16x8*>(bp + 32);
#pragma unroll
  for (int j = 0; j < NH; ++j) {
    bf16x8 nb0, nb1;
    if (j + 1 < NH) {                     // prefetch next B-frag
      nb0 = *reinterpret_cast<const bf16x8*>(bp + (j + 1) * 64);
      nb1 = *reinterpret_cast<const bf16x8*>(bp + (j + 1) * 64 + 32);
    }
    bf16x8 a0 = *reinterpret_cast<const bf16x8*>(ap + j * 64);
    bf16x8 a1 = *reinterpret_cast<const bf16x8*>(ap + j * 64 + 32);
    f32x4 acc = __builtin_amdgcn_mfma_f32_16x16x32_bf16(a0, b0, zero, 0, 0, 0);
    acc = __builtin_amdgcn_mfma_f32_16x16x32_bf16(a1, b1, acc, 0, 0, 0);
    ps[j] = acc;
    if (H == 0) {
      if (j == 0) {
        sacc = acc;
      } else {
#pragma unroll
        for (int e = 0; e < 4; ++e)
          sacc[e] = __builtin_amdgcn_fmed3f(sacc[e] + acc[e], QMINF, QMAXF);
      }
    }
    b0 = nb0;
    b1 = nb1;
  }
}

// ---- main: 1024 threads = 16 waves = 8 c-subtile pairs x 2 n-halves; 2 s-passes.
// R5 structure (staged dense 1KB NT stores -- R6 proved every store instr must
// cover full sectors; cross-instr partial-sector writes cost 1.45x WRITE amp).
// Single change vs R5: all post-A-build barriers are lgkm-only, so the NT store
// stream stays in flight across rounds (counted-vmcnt philosophy, T4).
__global__ __launch_bounds__(1024, 4) void satconv_kernel(
    const float* __restrict__ x, const unsigned short* __restrict__ bsign,
    const float* __restrict__ scale, float* __restrict__ y_out,
    float* __restrict__ psum_out) {
  extern __shared__ char smem[];
  unsigned short* Atile = (unsigned short*)smem;        // [16][KSTRIDE] bf16
  float* stage = (float*)(smem + STAGE_OFF);            // [8 pairs][2304] f32
  float* carryb = (float*)(smem + CARRY_OFF);           // [8][256] f32

  const int tid = threadIdx.x;
  const int bid = blockIdx.x;
  // XCD swizzle: 8 XCDs x 196 tiles; each XCD owns one batch image.
  const int m_tile = (bid & 7) * TILES_PER_IMG + (bid >> 3);
  const int m0 = m_tile << 4;

  // ---------- build A tile: lanes 0-15 = consecutive m (= consecutive ow) ----------
  {
    const int ml = tid & 15;
    const int grp = tid >> 4;                 // 0..63
    const int m = m0 + ml;
    const int b = m / L_SPATIAL;
    const int l = m - b * L_SPATIAL;
    const int oh = l / HW;
    const int ow = l - oh * HW;
    const float* xb = x + (size_t)b * (CIN * L_SPATIAL);
    unsigned short* arow = Atile + ml * KSTRIDE;
    for (int r = grp; r < 768; r += 64) {     // r = ci*3 + kh; 12 iters
      const int ci = r / 3;
      const int kh = r - ci * 3;
      const int hh = oh + kh - 1;
      const bool hv = ((unsigned)hh < (unsigned)HW);
      const float* xr = xb + (ci * HW + hh) * HW;
      const int kb = ci * 9 + kh * 3;
#pragma unroll
      for (int kw = 0; kw < 3; ++kw) {
        const int wv = ow + kw - 1;
        float v = 0.0f;
        if (hv && ((unsigned)wv < (unsigned)HW)) v = xr[wv];
        __hip_bfloat16 bv = __float2bfloat16(v);
        arow[kb + kw] = *reinterpret_cast<unsigned short*>(&bv);
      }
    }
  }

  const int lane = tid & 63;
  const int wave = tid >> 6;                  // 0..15
  const int cl = lane & 15;
  const int q = lane >> 4;
  const int cs = wave >> 1;                   // 0..7: c-subtile pair id
  const int h = wave & 1;                     // n-half

  // hoist scalar loads before the store streams
  const float sc_s0 = scale[cs * 16 + cl];
  const float sc_s1 = scale[128 + cs * 16 + cl];

  // precompute store-phase indices (R0 decode: f -> (qq, ci, n0))
  int base_it[9];
  {
#pragma unroll
    for (int it = 0; it < 9; ++it) {
      const int f = it * 256 + lane * 4;
      const int qq = f / 576;
      const int rem = f - qq * 576;
      const int ci = rem / 36;
      const int n0 = rem - ci * 36;
      base_it[it] = ((m0 + (qq << 2)) * COUT + ci) * NT + n0;
    }
  }

  __syncthreads();                            // A-tile ready (no stores in flight yet)

  const unsigned short* aptr = Atile + cl * KSTRIDE + q * 8;
  const int b_img = m0 / L_SPATIAL;           // WG never crosses batch boundary
  const int l0 = m0 - b_img * L_SPATIAL;
  float* reg = stage + cs * 2304;             // per-pair staging region

  for (int s = 0; s < 2; ++s) {
    const int csub0 = (s << 7) + (cs << 4);   // c-subtile base (0..240)
    const int c = csub0 + cl;
    const unsigned short* bptr = bsign + (size_t)c * K_TOTAL + q * 8;

    f32x4 ps[NH];
    f32x4 sacc = {0.0f, 0.0f, 0.0f, 0.0f};
    if (h == 0) compute18<0>(aptr, bptr, ps, sacc);
    else        compute18<1>(aptr, bptr, ps, sacc);

    // ---- carry hand-off: h0 -> h1 (per (cs, cl, q), f32x4 over the 4 m's) ----
    if (h == 0)
      *reinterpret_cast<f32x4*>(carryb + cs * 256 + lane * 4) = sacc;
    lgkm_barrier();                           // LDS-order only; stores stay in flight
    if (h == 1) {
      f32x4 cin = *reinterpret_cast<const f32x4*>(carryb + cs * 256 + lane * 4);
#pragma unroll
      for (int j = 0; j < NH; ++j) {
#pragma unroll
        for (int e = 0; e < 4; ++e)
          cin[e] = __builtin_amdgcn_fmed3f(cin[e] + ps[j][e], QMINF, QMAXF);
      }
      const float sc = (s == 0) ? sc_s0 : sc_s1;
      f32x4 yv;
#pragma unroll
      for (int e = 0; e < 4; ++e) yv[e] = cin[e] * sc;
      nt_store4(y_out + ((size_t)b_img * COUT + c) * L_SPATIAL + l0 + (q << 2), yv);
    }

    // ---- psum drain: 4 rg rounds; pair stages [q][16c][36n] (2304 f32), then
    // both waves copy out dense 1KB full-line NT stores (h0: it 0-4, h1: it 5-8).
    const int soff = csub0 * NT;
#pragma unroll
    for (int rg = 0; rg < 4; ++rg) {
      {
        // writer: 18 floats at reg[q*576 + cl*36 + h*18], vectorized b128/b64
        float* wr = reg + q * 576 + cl * 36 + h * NH;
        if (h == 0) {
          // base byte cl*144 + q*2304: 16B-aligned
          f32x4 v;
#pragma unroll
          for (int g = 0; g < 4; ++g) {
            v[0] = ps[4 * g + 0][rg]; v[1] = ps[4 * g + 1][rg];
            v[2] = ps[4 * g + 2][rg]; v[3] = ps[4 * g + 3][rg];
            *reinterpret_cast<f32x4*>(wr + 4 * g) = v;
          }
          f32x2 t = {ps[16][rg], ps[17][rg]};
          *reinterpret_cast<f32x2*>(wr + 16) = t;
        } else {
          // base byte ...+72: 8B-aligned; f32x2 then 4x f32x4 (16B-aligned)
          f32x2 t = {ps[0][rg], ps[1][rg]};
          *reinterpret_cast<f32x2*>(wr) = t;
          f32x4 v;
#pragma unroll
          for (int g = 0; g < 4; ++g) {
            v[0] = ps[4 * g + 2][rg]; v[1] = ps[4 * g + 3][rg];
            v[2] = ps[4 * g + 4][rg]; v[3] = ps[4 * g + 5][rg];
            *reinterpret_cast<f32x4*>(wr + 2 + 4 * g) = v;
          }
        }
      }
      lgkm_barrier();                         // stage visible; no vmcnt drain
      {
        const int rgoff = rg * ROWF + soff;
        const int it0 = (h == 0) ? 0 : 5;
        const int it1 = (h == 0) ? 5 : 9;
        for (int it = it0; it < it1; ++it) {
          f32x4 v = *reinterpret_cast<const f32x4*>(reg + it * 256 + lane * 4);
          nt_store4(psum_out + (size_t)(base_it[it] + rgoff), v);
        }
      }
      lgkm_barrier();                         // own ds_reads done -> stage reusable;
                                              // NT stores remain in flight
    }
  }
}

extern "C" void kernel_launch(void* const* d_in, const int* in_sizes, int n_in,
                              void* d_out, int out_size, void* d_ws, size_t ws_size,
                              hipStream_t stream) {
  const float* x = (const float*)d_in[0];
  const float* w = (const float*)d_in[1];
  float* y = (float*)d_out;
  float* psum = y + (size_t)BATCH * COUT * L_SPATIAL;            // y is 6,422,528 floats
  unsigned short* bsign = (unsigned short*)d_ws;                 // 256*2304*2 = 1,179,648 B
  float* scale = (float*)((char*)d_ws + (size_t)COUT * K_TOTAL * 2);

  prep_kernel<<<COUT, 256, 0, stream>>>(w, bsign, scale);

  hipFuncSetAttribute(reinterpret_cast<const void*>(satconv_kernel),
                      hipFuncAttributeMaxDynamicSharedMemorySize, LDS_BYTES);
  satconv_kernel<<<MT_TOTAL, 1024, LDS_BYTES, stream>>>(
      x, bsign, scale, y, psum);
}